// Round 3
// baseline (347.904 us; speedup 1.0000x reference)
//
#include <hip/hip_runtime.h>

#define B_ 8
#define N_ 16384
#define C_ 81
#define K_ 100
#define M_ (C_ * K_)          // 8100
#define NEG_ (-1e30f)
#define IOU_THR_ 0.5f
#define CAP_ 768              // per-(b,c) candidate list capacity
#define TAU0_ 0.96f           // class-0 threshold (bg rule depletes its tail)
#define TAU_ 0.985f           // classes >= 1
#define KCAP_ 256             // k4 compaction capacity

// monotone key: order of key_of(v) == order of v (all floats)
__device__ inline unsigned key_of(float v) {
  unsigned u = __float_as_uint(v);
  return u ^ ((unsigned)((int)u >> 31) | 0x80000000u);
}

__device__ inline void find_kth_bin(unsigned* hist, unsigned* scan, unsigned kth,
                                    unsigned* out_b, unsigned* out_g) {
  int tid = threadIdx.x;
  int base = tid << 4;
  unsigned local = 0;
#pragma unroll
  for (int i = 0; i < 16; ++i) local += hist[base + ((tid + i) & 15)];
  scan[tid] = local;
  __syncthreads();
  for (int off = 1; off < 256; off <<= 1) {
    unsigned add = (tid + off < 256) ? scan[tid + off] : 0u;
    __syncthreads();
    scan[tid] += add;
    __syncthreads();
  }
  unsigned inclusive = scan[tid];
  unsigned after = inclusive - local;
  if (after < kth && inclusive >= kth) {
    unsigned g = after;
    for (int b = 15; b >= 0; --b) {
      unsigned c = hist[base + b];
      if (g + c >= kth) { *out_b = (unsigned)(base + b); *out_g = g; break; }
      g += c;
    }
  }
  __syncthreads();
}

// ---------------- kA: background bitmask (argmax==0 <=> p[0] >= max(rest)) --------
__global__ __launch_bounds__(256) void kA_bg(const float* __restrict__ probs,
                                             unsigned* __restrict__ bgmask) {
  int t = blockIdx.x * 256 + threadIdx.x;     // 0 .. B*N/4 - 1
  int R = t << 2;                             // flat row b*N+n, 4 rows per thread
  const float4* p4 = (const float4*)(probs + (size_t)R * C_);  // 1296B-aligned
  float c0[4], m[4];
#pragma unroll
  for (int r = 0; r < 4; ++r) { c0[r] = 0.0f; m[r] = -1.0f; }
#pragma unroll
  for (int i = 0; i < 81; ++i) {              // 81 float4 = 324 floats = 4 rows
    float4 v = p4[i];
    float a[4] = {v.x, v.y, v.z, v.w};
#pragma unroll
    for (int j = 0; j < 4; ++j) {
      int f = 4 * i + j;                      // static after unroll
      int r = f / 81, col = f % 81;
      if (col == 0) c0[r] = a[j];
      else m[r] = fmaxf(m[r], a[j]);
    }
  }
  unsigned bits = 0;
#pragma unroll
  for (int r = 0; r < 4; ++r) if (c0[r] >= m[r]) bits |= (1u << r);
  if (bits) atomicOr(&bgmask[R >> 5], bits << (R & 31));
}

// ---------------- kB: threshold candidate generation (coalesced flat pass) --------
__global__ __launch_bounds__(256) void kB_cand(const float* __restrict__ probs,
                                               const unsigned* __restrict__ bgmask,
                                               unsigned* __restrict__ cnt,
                                               float* __restrict__ cand_val,
                                               int* __restrict__ cand_idx) {
  const float4* p4 = (const float4*)probs;
  int t = blockIdx.x * 256 + threadIdx.x;     // 2592 blocks -> 663552 threads
  const int STRIDE = 2592 * 256;
#pragma unroll
  for (int g = 0; g < 4; ++g) {
    int i = t + g * STRIDE;                   // covers B*N*C/4 exactly
    float4 v = p4[i];
    float a[4] = {v.x, v.y, v.z, v.w};
#pragma unroll
    for (int j = 0; j < 4; ++j) {
      float val = a[j];
      if (val > TAU0_) {
        int f = 4 * i + j;
        int bn = f / C_;                      // b*N + n (magic-mul div)
        int c = f - bn * C_;
        if (c == 0 || val > TAU_) {
          unsigned w = bgmask[bn >> 5];
          if (!((w >> (bn & 31)) & 1u)) {
            int b = bn >> 14;
            int n = bn & (N_ - 1);
            int bc = b * C_ + c;
            unsigned slot = atomicAdd(&cnt[bc], 1u);
            if (slot < CAP_) {
              cand_val[bc * CAP_ + slot] = val;
              cand_idx[bc * CAP_ + slot] = n;
            }
          }
        }
      }
    }
  }
}

// ---------------- k_sel: per-(b,c) exact top-100 + decode + wave NMS --------------
__global__ __launch_bounds__(256) void k_sel(const float* __restrict__ probs,
                                             const unsigned* __restrict__ bgmask,
                                             const unsigned* __restrict__ cnt,
                                             const float* __restrict__ cand_val,
                                             const int* __restrict__ cand_idx,
                                             const float* __restrict__ roi,
                                             const float* __restrict__ deltas,
                                             float* __restrict__ top_sc,
                                             float* __restrict__ top_box,
                                             int* __restrict__ keep_out) {
  int bc = blockIdx.x;
  int b = bc / C_, c = bc % C_;
  int tid = threadIdx.x;
  __shared__ float cv[CAP_];
  __shared__ int   ci[CAP_];
  __shared__ float selv[K_];
  __shared__ int   seli[K_];
  __shared__ float bx0[K_], bx1[K_], bx2[K_], bx3[K_], bar[K_];
  __shared__ unsigned chosen[N_ / 32];        // fallback-only (2 KB)
  __shared__ float rv[4];
  __shared__ int   ri[4];

  unsigned n_cand = cnt[bc];
  bool fast = (n_cand >= (unsigned)K_ && n_cand <= (unsigned)CAP_);
  if (fast) {
    int cn = (int)n_cand;
    for (int t = tid; t < cn; t += 256) {
      cv[t] = cand_val[bc * CAP_ + t];
      ci[t] = cand_idx[bc * CAP_ + t];
    }
    __syncthreads();
    for (int t = tid; t < cn; t += 256) {
      float mv = cv[t];
      int   mi = ci[t];
      int rank = 0;
      for (int j = 0; j < cn; ++j) {
        float v = cv[j]; int ji = ci[j];
        rank += (v > mv || (v == mv && ji < mi)) ? 1 : 0;
      }
      if (rank < K_) { selv[rank] = mv; seli[rank] = mi; }
    }
    __syncthreads();
  } else {
    // exact fallback: iterative top-100 over full score column (never taken stat.)
    for (int i = tid; i < N_ / 32; i += 256) chosen[i] = 0u;
    __syncthreads();
    for (int k = 0; k < K_; ++k) {
      float bv = -1.0f;
      int   bi = 0;
      for (int n = tid; n < N_; n += 256) {
        if ((chosen[n >> 5] >> (n & 31)) & 1u) continue;
        unsigned w = bgmask[(((unsigned)b << 14) + n) >> 5];
        float v = ((w >> (n & 31)) & 1u) ? 0.0f
                                         : probs[((size_t)((b << 14) + n)) * C_ + c];
        if (v > bv || (v == bv && n < bi)) { bv = v; bi = n; }
      }
      int lane = tid & 63, wave = tid >> 6;
      for (int off = 32; off > 0; off >>= 1) {
        float ov = __shfl_down(bv, off);
        int   oi = __shfl_down(bi, off);
        if (ov > bv || (ov == bv && oi < bi)) { bv = ov; bi = oi; }
      }
      if (lane == 0) { rv[wave] = bv; ri[wave] = bi; }
      __syncthreads();
      if (tid == 0) {
        float fv = rv[0]; int fi = ri[0];
        for (int w2 = 1; w2 < 4; ++w2)
          if (rv[w2] > fv || (rv[w2] == fv && ri[w2] < fi)) { fv = rv[w2]; fi = ri[w2]; }
        selv[k] = fv; seli[k] = fi;
        chosen[fi >> 5] |= (1u << (fi & 31));
      }
      __syncthreads();
    }
  }

  // decode + clip selected boxes; write top_sc/top_box
  if (tid < K_) {
    int n = seli[tid];
    float4 a = *(const float4*)(roi + (((size_t)b << 14) + n) * 4);
    float4 d = *(const float4*)(deltas + (((size_t)b << 14) + n) * (C_ * 4) + (c << 2));
    float aw = a.w - a.y, ah = a.z - a.x;
    float acx = a.y + 0.5f * aw, acy = a.x + 0.5f * ah;
    float d0 = d.x * 0.1f, d1 = d.y * 0.1f, d2 = d.z * 0.2f, d3 = d.w * 0.2f;
    float bw = expf(d3) * aw, bh = expf(d2) * ah;
    float bcx = d1 * aw + acx, bcy = d0 * ah + acy;
    float y1 = bcy - 0.5f * bh, x1 = bcx - 0.5f * bw;
    float y2 = bh + y1, x2 = bw + x1;
    y1 = fminf(fmaxf(y1, 0.0f), 1.0f);
    x1 = fminf(fmaxf(x1, 0.0f), 1.0f);
    y2 = fminf(fmaxf(y2, 0.0f), 1.0f);
    x2 = fminf(fmaxf(x2, 0.0f), 1.0f);
    bx0[tid] = y1; bx1[tid] = x1; bx2[tid] = y2; bx3[tid] = x2;
    bar[tid] = (y2 - y1) * (x2 - x1);
    top_sc[bc * K_ + tid] = selv[tid];
    *(float4*)(top_box + ((size_t)bc * K_ + tid) * 4) = make_float4(y1, x1, y2, x2);
  }
  __syncthreads();

  // single-wave barrier-free NMS (wave 0; 2 boxes per lane)
  if (tid < 64) {
    float Ay1 = bx0[tid], Ax1 = bx1[tid], Ay2 = bx2[tid], Ax2 = bx3[tid], Aar = bar[tid];
    int hasB = (tid + 64 < K_);
    float By1 = 0, Bx1v = 0, By2 = 0, Bx2v = 0, Bar2 = 0;
    if (hasB) { By1 = bx0[tid+64]; Bx1v = bx1[tid+64]; By2 = bx2[tid+64]; Bx2v = bx3[tid+64]; Bar2 = bar[tid+64]; }
    int ka = 1, kb = hasB;
    for (int i = 0; i < K_; ++i) {
      int src = i & 63;
      bool hi = (i >= 64);
      float iy1 = __shfl(hi ? By1 : Ay1, src);
      float ix1 = __shfl(hi ? Bx1v : Ax1, src);
      float iy2 = __shfl(hi ? By2 : Ay2, src);
      float ix2 = __shfl(hi ? Bx2v : Ax2, src);
      float iar = __shfl(hi ? Bar2 : Aar, src);
      int   ki  = __shfl(hi ? kb : ka, src);
      if (ki) {
        if (ka && tid > i) {
          float yy1 = fmaxf(iy1, Ay1), xx1 = fmaxf(ix1, Ax1);
          float yy2 = fminf(iy2, Ay2), xx2 = fminf(ix2, Ax2);
          float inter = fmaxf(yy2 - yy1, 0.0f) * fmaxf(xx2 - xx1, 0.0f);
          float uni = iar + Aar - inter;
          if (inter / fmaxf(uni, 1e-12f) > IOU_THR_) ka = 0;
        }
        if (kb && (tid + 64) > i) {
          float yy1 = fmaxf(iy1, By1), xx1 = fmaxf(ix1, Bx1v);
          float yy2 = fminf(iy2, By2), xx2 = fminf(ix2, Bx2v);
          float inter = fmaxf(yy2 - yy1, 0.0f) * fmaxf(xx2 - xx1, 0.0f);
          float uni = iar + Bar2 - inter;
          if (inter / fmaxf(uni, 1e-12f) > IOU_THR_) kb = 0;
        }
      }
    }
    keep_out[bc * K_ + tid] = ka;
    if (hasB) keep_out[bc * K_ + tid + 64] = kb;
  }
}

// ---------------- k4: per-batch exact top-100 over 8100 keyed values --------------
__global__ __launch_bounds__(256) void k4_final(const float* __restrict__ top_sc,
                                                const float* __restrict__ top_box,
                                                const int* __restrict__ keep_in,
                                                float* __restrict__ out) {
  int b = blockIdx.x;
  int tid = threadIdx.x;
  __shared__ float keyed[M_];
  __shared__ unsigned hist[4096];
  __shared__ unsigned scan[256];
  __shared__ unsigned s_b1, s_g1, s_b2, s_g2, s_cnt;
  __shared__ float cv[KCAP_];
  __shared__ int   ci[KCAP_];
  __shared__ int   sel_m[K_];
  __shared__ float sel_v[K_];

  for (int m = tid; m < M_; m += 256)
    keyed[m] = keep_in[b * M_ + m] ? top_sc[b * M_ + m] : NEG_;
  for (int i = tid; i < 4096; i += 256) hist[i] = 0;
  if (tid == 0) s_cnt = 0;
  __syncthreads();
  for (int m = tid; m < M_; m += 256) atomicAdd(&hist[key_of(keyed[m]) >> 20], 1u);
  __syncthreads();
  find_kth_bin(hist, scan, K_, &s_b1, &s_g1);
  unsigned b1 = s_b1;
  unsigned need1 = K_ - s_g1;
  __syncthreads();
  for (int i = tid; i < 4096; i += 256) hist[i] = 0;
  __syncthreads();
  for (int m = tid; m < M_; m += 256) {
    unsigned k = key_of(keyed[m]);
    if ((k >> 20) == b1) atomicAdd(&hist[(k >> 8) & 0xFFFu], 1u);
  }
  __syncthreads();
  find_kth_bin(hist, scan, need1, &s_b2, &s_g2);
  unsigned t24 = (b1 << 12) | s_b2;
  __syncthreads();
  for (int m = tid; m < M_; m += 256) {
    float v = keyed[m];
    unsigned k = key_of(v);
    if ((k >> 8) >= t24) {
      unsigned p = atomicAdd(&s_cnt, 1u);
      if (p < KCAP_) { cv[p] = v; ci[p] = m; }
    }
  }
  __syncthreads();
  int cnt = (int)min(s_cnt, (unsigned)KCAP_);
  if (tid < cnt) {
    float mv = cv[tid];
    int   mi = ci[tid];
    int rank = 0;
    for (int j = 0; j < cnt; ++j) {
      float v = cv[j]; int ji = ci[j];
      rank += (v > mv || (v == mv && ji < mi)) ? 1 : 0;
    }
    if (rank < K_) { sel_m[rank] = mi; sel_v[rank] = mv; }
  }
  __syncthreads();

  float* ob = out;                 // (B,K,4)
  float* oc = out + B_ * K_ * 4;   // (B,K)
  float* os = oc + B_ * K_;        // (B,K)
  if (tid < K_) {
    int m = sel_m[tid];
    float kv = sel_v[tid];
    bool valid = kv > (NEG_ * 0.5f);
    float4 bb = *(const float4*)(top_box + ((size_t)b * M_ + m) * 4);
    float sv = top_sc[b * M_ + m];
    float cls = (float)(m / K_);
    float4 o = valid ? bb : make_float4(0.f, 0.f, 0.f, 0.f);
    *(float4*)(ob + ((size_t)b * K_ + tid) * 4) = o;
    oc[b * K_ + tid] = valid ? cls : 0.0f;
    os[b * K_ + tid] = valid ? sv : 0.0f;
  }
}

extern "C" void kernel_launch(void* const* d_in, const int* in_sizes, int n_in,
                              void* d_out, int out_size, void* d_ws, size_t ws_size,
                              hipStream_t stream) {
  const float* roi    = (const float*)d_in[0];   // (B,N,4)
  const float* deltas = (const float*)d_in[1];   // (B,N,C*4)
  const float* probs  = (const float*)d_in[2];   // (B,N,C)
  float* out = (float*)d_out;

  char* ws = (char*)d_ws;
  unsigned* cnt    = (unsigned*)ws;                         // 648 u32 (pad to 1024)
  unsigned* bgmask = (unsigned*)(ws + 1024 * 4);            // B*N/32 = 4096 u32
  size_t off = (1024 + 4096) * 4;
  float* cand_val = (float*)(ws + off); off += (size_t)B_ * C_ * CAP_ * sizeof(float);
  int*   cand_idx = (int*)(ws + off);   off += (size_t)B_ * C_ * CAP_ * sizeof(int);
  float* top_sc   = (float*)(ws + off); off += (size_t)B_ * M_ * sizeof(float);
  float* top_box  = (float*)(ws + off); off += (size_t)B_ * M_ * 4 * sizeof(float);
  int*   keepA    = (int*)(ws + off);   off += (size_t)B_ * M_ * sizeof(int);
  (void)ws_size; (void)in_sizes; (void)n_in; (void)out_size;

  hipMemsetAsync(ws, 0, (1024 + 4096) * 4, stream);         // cnt + bgmask
  kA_bg<<<(B_ * N_ / 4) / 256, 256, 0, stream>>>(probs, bgmask);
  kB_cand<<<2592, 256, 0, stream>>>(probs, bgmask, cnt, cand_val, cand_idx);
  k_sel<<<B_ * C_, 256, 0, stream>>>(probs, bgmask, cnt, cand_val, cand_idx,
                                     roi, deltas, top_sc, top_box, keepA);
  k4_final<<<B_, 256, 0, stream>>>(top_sc, top_box, keepA, out);
}

// Round 4
// 137.139 us; speedup vs baseline: 2.5369x; 2.5369x over previous
//
#include <hip/hip_runtime.h>

#define B_ 8
#define N_ 16384
#define C_ 81
#define K_ 100
#define M_ (C_ * K_)          // 8100
#define NEG_ (-1e30f)
#define IOU_THR_ 0.5f
#define TAU0_ 0.96f           // class-0 threshold (bg rule depletes its tail)
#define TAU_ 0.985f           // classes >= 1
#define CHUNK_ 128            // rows per kFused block
#define NCHUNK_ (N_ / CHUNK_) // 128
#define CAPC_ 32              // per-class per-chunk candidate cap
#define CAP_ 768              // k_sel gather capacity
#define KCAP_ 256             // k4 compaction capacity

// monotone key: order of key_of(v) == order of v (all floats)
__device__ inline unsigned key_of(float v) {
  unsigned u = __float_as_uint(v);
  return u ^ ((unsigned)((int)u >> 31) | 0x80000000u);
}

__device__ inline void find_kth_bin(unsigned* hist, unsigned* scan, unsigned kth,
                                    unsigned* out_b, unsigned* out_g) {
  int tid = threadIdx.x;
  int base = tid << 4;
  unsigned local = 0;
#pragma unroll
  for (int i = 0; i < 16; ++i) local += hist[base + ((tid + i) & 15)];
  scan[tid] = local;
  __syncthreads();
  for (int off = 1; off < 256; off <<= 1) {
    unsigned add = (tid + off < 256) ? scan[tid + off] : 0u;
    __syncthreads();
    scan[tid] += add;
    __syncthreads();
  }
  unsigned inclusive = scan[tid];
  unsigned after = inclusive - local;
  if (after < kth && inclusive >= kth) {
    unsigned g = after;
    for (int b = 15; b >= 0; --b) {
      unsigned c = hist[base + b];
      if (g + c >= kth) { *out_b = (unsigned)(base + b); *out_g = g; break; }
      g += c;
    }
  }
  __syncthreads();
}

// ---- kFused: one coalesced pass over probs -> bg bits + per-(b,c,chunk) candidates
__global__ __launch_bounds__(128) void kFused(const float* __restrict__ probs,
                                              unsigned long long* __restrict__ bgm,
                                              unsigned* __restrict__ pcnt,
                                              float* __restrict__ cand_val,
                                              int* __restrict__ cand_idx) {
  int gid = blockIdx.x;            // 0..1023
  int b = gid >> 7;                // / NCHUNK_
  int q = gid & (NCHUNK_ - 1);
  int tid = threadIdx.x;           // 0..127

  __shared__ float tile[CHUNK_ * C_];       // 128*81*4 = 41.5 KB
  __shared__ unsigned lcnt[C_];
  __shared__ float lval[C_][CAPC_];
  __shared__ int   lidx[C_][CAPC_];

  // stage 128 rows (coalesced float4; base is 16B-aligned: 128*324B = 2592*16B)
  const float4* src4 = (const float4*)(probs + ((size_t)b * N_ + (size_t)q * CHUNK_) * C_);
  float4* tile4 = (float4*)tile;
  for (int i = tid; i < (CHUNK_ * C_) / 4; i += 128) tile4[i] = src4[i];
  if (tid < C_) lcnt[tid] = 0;
  __syncthreads();

  // per-thread row: bg test + candidate emission
  const float* myrow = &tile[tid * C_];
  float p0 = myrow[0];
  float mx = myrow[1];
  for (int j = 2; j < C_; ++j) mx = fmaxf(mx, myrow[j]);
  bool bg = (p0 >= mx);
  unsigned long long bal = __ballot(bg);
  if ((tid & 63) == 0)
    bgm[((size_t)b * N_ + (size_t)q * CHUNK_ + (tid & 64)) >> 6] = bal;
  if (!bg) {
    int n = q * CHUNK_ + tid;      // row index within batch b
    for (int j = 0; j < C_; ++j) {
      float v = myrow[j];
      float thr = (j == 0) ? TAU0_ : TAU_;
      if (v > thr) {
        unsigned s = atomicAdd(&lcnt[j], 1u);   // LDS atomic (fast)
        if (s < CAPC_) { lval[j][s] = v; lidx[j][s] = n; }
      }
    }
  }
  __syncthreads();

  // flush: deterministic segment per (b,c,chunk); raw count (overflow detectable)
  if (tid < C_) {
    unsigned lc = lcnt[tid];
    unsigned wr = lc < CAPC_ ? lc : CAPC_;
    size_t seg = ((size_t)(b * C_ + tid) * NCHUNK_ + q);
    pcnt[seg] = lc;
    float* dv = cand_val + seg * CAPC_;
    int*   di = cand_idx + seg * CAPC_;
    for (unsigned s = 0; s < wr; ++s) { dv[s] = lval[tid][s]; di[s] = lidx[tid][s]; }
  }
}

// ---- k_sel: per-(b,c) exact top-100 + decode + single-wave NMS --------------------
__global__ __launch_bounds__(256) void k_sel(const float* __restrict__ probs,
                                             const unsigned long long* __restrict__ bgm,
                                             const unsigned* __restrict__ pcnt,
                                             const float* __restrict__ cand_val,
                                             const int* __restrict__ cand_idx,
                                             const float* __restrict__ roi,
                                             const float* __restrict__ deltas,
                                             float* __restrict__ top_sc,
                                             float* __restrict__ top_box,
                                             int* __restrict__ keep_out) {
  int bc = blockIdx.x;
  int b = bc / C_, c = bc % C_;
  int tid = threadIdx.x;
  __shared__ float cv[CAP_];
  __shared__ int   ci[CAP_];
  __shared__ unsigned spc[NCHUNK_];
  __shared__ int     spre[NCHUNK_ + 1];
  __shared__ int     s_total;
  __shared__ int     s_ovf;
  __shared__ float selv[K_];
  __shared__ int   seli[K_];
  __shared__ float bx0[K_], bx1[K_], bx2[K_], bx3[K_], bar[K_];
  __shared__ unsigned chosen[N_ / 32];   // fallback only (2 KB)
  __shared__ float rv[4];
  __shared__ int   ri[4];

  if (tid == 0) s_ovf = 0;
  for (int t = tid; t < NCHUNK_; t += 256) {
    unsigned lc = pcnt[(size_t)bc * NCHUNK_ + t];
    spc[t] = lc;
    if (lc > CAPC_) atomicOr(&s_ovf, 1);   // LDS atomic, cold
  }
  __syncthreads();
  if (tid == 0) {
    int acc = 0;
    for (int qq = 0; qq < NCHUNK_; ++qq) {
      spre[qq] = acc;
      unsigned lc = spc[qq];
      acc += (int)(lc < CAPC_ ? lc : CAPC_);
    }
    spre[NCHUNK_] = acc;
    s_total = acc;
  }
  __syncthreads();
  int total = s_total;
  bool fast = (!s_ovf && total >= K_ && total <= CAP_);

  if (fast) {
    for (int t = tid; t < NCHUNK_ * CAPC_; t += 256) {
      int qq = t >> 5, s = t & (CAPC_ - 1);
      if ((unsigned)s < spc[qq]) {
        size_t seg = (size_t)bc * NCHUNK_ + qq;
        int pos = spre[qq] + s;
        cv[pos] = cand_val[seg * CAPC_ + s];
        ci[pos] = cand_idx[seg * CAPC_ + s];
      }
    }
    __syncthreads();
    for (int t = tid; t < total; t += 256) {
      float mv = cv[t];
      int   mi = ci[t];
      int rank = 0;
      for (int j = 0; j < total; ++j) {
        float v = cv[j]; int ji = ci[j];
        rank += (v > mv || (v == mv && ji < mi)) ? 1 : 0;
      }
      if (rank < K_) { selv[rank] = mv; seli[rank] = mi; }
    }
    __syncthreads();
  } else {
    // exact fallback: iterative top-100 over the full score column (stat. never taken)
    for (int i = tid; i < N_ / 32; i += 256) chosen[i] = 0u;
    __syncthreads();
    for (int k = 0; k < K_; ++k) {
      float bv = -1.0f;
      int   bi = 0;
      for (int n = tid; n < N_; n += 256) {
        if ((chosen[n >> 5] >> (n & 31)) & 1u) continue;
        unsigned long long w = bgm[((size_t)b * N_ + n) >> 6];
        float v = ((w >> (n & 63)) & 1ull) ? 0.0f
                 : probs[((size_t)b * N_ + n) * C_ + c];
        if (v > bv || (v == bv && n < bi)) { bv = v; bi = n; }
      }
      int lane = tid & 63, wave = tid >> 6;
      for (int off = 32; off > 0; off >>= 1) {
        float ov = __shfl_down(bv, off);
        int   oi = __shfl_down(bi, off);
        if (ov > bv || (ov == bv && oi < bi)) { bv = ov; bi = oi; }
      }
      if (lane == 0) { rv[wave] = bv; ri[wave] = bi; }
      __syncthreads();
      if (tid == 0) {
        float fv = rv[0]; int fi = ri[0];
        for (int w2 = 1; w2 < 4; ++w2)
          if (rv[w2] > fv || (rv[w2] == fv && ri[w2] < fi)) { fv = rv[w2]; fi = ri[w2]; }
        selv[k] = fv; seli[k] = fi;
        chosen[fi >> 5] |= (1u << (fi & 31));
      }
      __syncthreads();
    }
  }

  // decode + clip; write top_sc/top_box
  if (tid < K_) {
    int n = seli[tid];
    float4 a = *(const float4*)(roi + ((size_t)b * N_ + n) * 4);
    float4 d = *(const float4*)(deltas + ((size_t)b * N_ + n) * (C_ * 4) + (c << 2));
    float aw = a.w - a.y, ah = a.z - a.x;
    float acx = a.y + 0.5f * aw, acy = a.x + 0.5f * ah;
    float d0 = d.x * 0.1f, d1 = d.y * 0.1f, d2 = d.z * 0.2f, d3 = d.w * 0.2f;
    float bw = expf(d3) * aw, bh = expf(d2) * ah;
    float bcx = d1 * aw + acx, bcy = d0 * ah + acy;
    float y1 = bcy - 0.5f * bh, x1 = bcx - 0.5f * bw;
    float y2 = bh + y1, x2 = bw + x1;
    y1 = fminf(fmaxf(y1, 0.0f), 1.0f);
    x1 = fminf(fmaxf(x1, 0.0f), 1.0f);
    y2 = fminf(fmaxf(y2, 0.0f), 1.0f);
    x2 = fminf(fmaxf(x2, 0.0f), 1.0f);
    bx0[tid] = y1; bx1[tid] = x1; bx2[tid] = y2; bx3[tid] = x2;
    bar[tid] = (y2 - y1) * (x2 - x1);
    top_sc[bc * K_ + tid] = selv[tid];
    *(float4*)(top_box + ((size_t)bc * K_ + tid) * 4) = make_float4(y1, x1, y2, x2);
  }
  __syncthreads();

  // single-wave barrier-free NMS (wave 0; 2 boxes per lane)
  if (tid < 64) {
    float Ay1 = bx0[tid], Ax1 = bx1[tid], Ay2 = bx2[tid], Ax2 = bx3[tid], Aar = bar[tid];
    int hasB = (tid + 64 < K_);
    float By1 = 0, Bxx1 = 0, By2 = 0, Bxx2 = 0, Bar2 = 0;
    if (hasB) { By1 = bx0[tid+64]; Bxx1 = bx1[tid+64]; By2 = bx2[tid+64]; Bxx2 = bx3[tid+64]; Bar2 = bar[tid+64]; }
    int ka = 1, kb = hasB;
    for (int i = 0; i < K_; ++i) {
      int src = i & 63;
      bool hi = (i >= 64);
      float iy1 = __shfl(hi ? By1 : Ay1, src);
      float ix1 = __shfl(hi ? Bxx1 : Ax1, src);
      float iy2 = __shfl(hi ? By2 : Ay2, src);
      float ix2 = __shfl(hi ? Bxx2 : Ax2, src);
      float iar = __shfl(hi ? Bar2 : Aar, src);
      int   ki  = __shfl(hi ? kb : ka, src);
      if (ki) {
        if (ka && tid > i) {
          float yy1 = fmaxf(iy1, Ay1), xx1 = fmaxf(ix1, Ax1);
          float yy2 = fminf(iy2, Ay2), xx2 = fminf(ix2, Ax2);
          float inter = fmaxf(yy2 - yy1, 0.0f) * fmaxf(xx2 - xx1, 0.0f);
          float uni = iar + Aar - inter;
          if (inter / fmaxf(uni, 1e-12f) > IOU_THR_) ka = 0;
        }
        if (kb && (tid + 64) > i) {
          float yy1 = fmaxf(iy1, By1), xx1 = fmaxf(ix1, Bxx1);
          float yy2 = fminf(iy2, By2), xx2 = fminf(ix2, Bxx2);
          float inter = fmaxf(yy2 - yy1, 0.0f) * fmaxf(xx2 - xx1, 0.0f);
          float uni = iar + Bar2 - inter;
          if (inter / fmaxf(uni, 1e-12f) > IOU_THR_) kb = 0;
        }
      }
    }
    keep_out[bc * K_ + tid] = ka;
    if (hasB) keep_out[bc * K_ + tid + 64] = kb;
  }
}

// ---- k4: per-batch exact top-100 over 8100 keyed values ---------------------------
__global__ __launch_bounds__(256) void k4_final(const float* __restrict__ top_sc,
                                                const float* __restrict__ top_box,
                                                const int* __restrict__ keep_in,
                                                float* __restrict__ out) {
  int b = blockIdx.x;
  int tid = threadIdx.x;
  __shared__ float keyed[M_];
  __shared__ unsigned hist[4096];
  __shared__ unsigned scan[256];
  __shared__ unsigned s_b1, s_g1, s_b2, s_g2, s_cnt;
  __shared__ float cv[KCAP_];
  __shared__ int   ci[KCAP_];
  __shared__ int   sel_m[K_];
  __shared__ float sel_v[K_];

  for (int m = tid; m < M_; m += 256)
    keyed[m] = keep_in[b * M_ + m] ? top_sc[b * M_ + m] : NEG_;
  for (int i = tid; i < 4096; i += 256) hist[i] = 0;
  if (tid == 0) s_cnt = 0;
  __syncthreads();
  for (int m = tid; m < M_; m += 256) atomicAdd(&hist[key_of(keyed[m]) >> 20], 1u);
  __syncthreads();
  find_kth_bin(hist, scan, K_, &s_b1, &s_g1);
  unsigned b1 = s_b1;
  unsigned need1 = K_ - s_g1;
  __syncthreads();
  for (int i = tid; i < 4096; i += 256) hist[i] = 0;
  __syncthreads();
  for (int m = tid; m < M_; m += 256) {
    unsigned k = key_of(keyed[m]);
    if ((k >> 20) == b1) atomicAdd(&hist[(k >> 8) & 0xFFFu], 1u);
  }
  __syncthreads();
  find_kth_bin(hist, scan, need1, &s_b2, &s_g2);
  unsigned t24 = (b1 << 12) | s_b2;
  __syncthreads();
  for (int m = tid; m < M_; m += 256) {
    float v = keyed[m];
    unsigned k = key_of(v);
    if ((k >> 8) >= t24) {
      unsigned p = atomicAdd(&s_cnt, 1u);
      if (p < KCAP_) { cv[p] = v; ci[p] = m; }
    }
  }
  __syncthreads();
  int cnt = (int)min(s_cnt, (unsigned)KCAP_);
  if (tid < cnt) {
    float mv = cv[tid];
    int   mi = ci[tid];
    int rank = 0;
    for (int j = 0; j < cnt; ++j) {
      float v = cv[j]; int ji = ci[j];
      rank += (v > mv || (v == mv && ji < mi)) ? 1 : 0;
    }
    if (rank < K_) { sel_m[rank] = mi; sel_v[rank] = mv; }
  }
  __syncthreads();

  float* ob = out;                 // (B,K,4)
  float* oc = out + B_ * K_ * 4;   // (B,K)
  float* os = oc + B_ * K_;        // (B,K)
  if (tid < K_) {
    int m = sel_m[tid];
    float kv = sel_v[tid];
    bool valid = kv > (NEG_ * 0.5f);
    float4 bb = *(const float4*)(top_box + ((size_t)b * M_ + m) * 4);
    float sv = top_sc[b * M_ + m];
    float cls = (float)(m / K_);
    float4 o = valid ? bb : make_float4(0.f, 0.f, 0.f, 0.f);
    *(float4*)(ob + ((size_t)b * K_ + tid) * 4) = o;
    oc[b * K_ + tid] = valid ? cls : 0.0f;
    os[b * K_ + tid] = valid ? sv : 0.0f;
  }
}

extern "C" void kernel_launch(void* const* d_in, const int* in_sizes, int n_in,
                              void* d_out, int out_size, void* d_ws, size_t ws_size,
                              hipStream_t stream) {
  const float* roi    = (const float*)d_in[0];   // (B,N,4)
  const float* deltas = (const float*)d_in[1];   // (B,N,C*4)
  const float* probs  = (const float*)d_in[2];   // (B,N,C)
  float* out = (float*)d_out;

  char* ws = (char*)d_ws;
  size_t off = 0;
  unsigned long long* bgm = (unsigned long long*)(ws + off);
  off += (size_t)B_ * N_ / 64 * sizeof(unsigned long long);         // 16 KB
  unsigned* pcnt = (unsigned*)(ws + off);
  off += (size_t)B_ * C_ * NCHUNK_ * sizeof(unsigned);              // 324 KB
  float* cand_val = (float*)(ws + off);
  off += (size_t)B_ * C_ * NCHUNK_ * CAPC_ * sizeof(float);         // 10.6 MB
  int* cand_idx = (int*)(ws + off);
  off += (size_t)B_ * C_ * NCHUNK_ * CAPC_ * sizeof(int);           // 10.6 MB
  float* top_sc = (float*)(ws + off);  off += (size_t)B_ * M_ * sizeof(float);
  float* top_box = (float*)(ws + off); off += (size_t)B_ * M_ * 4 * sizeof(float);
  int* keepA = (int*)(ws + off);       off += (size_t)B_ * M_ * sizeof(int);
  (void)ws_size; (void)in_sizes; (void)n_in; (void)out_size;

  kFused<<<B_ * NCHUNK_, CHUNK_, 0, stream>>>(probs, bgm, pcnt, cand_val, cand_idx);
  k_sel<<<B_ * C_, 256, 0, stream>>>(probs, bgm, pcnt, cand_val, cand_idx,
                                     roi, deltas, top_sc, top_box, keepA);
  k4_final<<<B_, 256, 0, stream>>>(top_sc, top_box, keepA, out);
}

// Round 5
// 118.594 us; speedup vs baseline: 2.9336x; 1.1564x over previous
//
#include <hip/hip_runtime.h>

#define B_ 8
#define N_ 16384
#define C_ 81
#define K_ 100
#define M_ (C_ * K_)          // 8100
#define NEG_ (-1e30f)
#define IOU_THR_ 0.5f
#define TAU0_ 0.96f           // class-0 threshold (bg rule depletes its tail)
#define TAU_ 0.985f           // classes >= 1
#define CHUNK_ 128            // rows per kFused block
#define NCHUNK_ (N_ / CHUNK_) // 128
#define CAPC_ 16              // per-class per-chunk candidate cap (Poisson lam<=3.6)
#define CAP_ 768              // k_sel gather capacity
#define KCAP_ 256             // k4 compaction capacity

// monotone key: order of key_of(v) == order of v (all floats)
__device__ inline unsigned key_of(float v) {
  unsigned u = __float_as_uint(v);
  return u ^ ((unsigned)((int)u >> 31) | 0x80000000u);
}

__device__ inline void find_kth_bin(unsigned* hist, unsigned* scan, unsigned kth,
                                    unsigned* out_b, unsigned* out_g) {
  int tid = threadIdx.x;
  int base = tid << 4;
  unsigned local = 0;
#pragma unroll
  for (int i = 0; i < 16; ++i) local += hist[base + ((tid + i) & 15)];
  scan[tid] = local;
  __syncthreads();
  for (int off = 1; off < 256; off <<= 1) {
    unsigned add = (tid + off < 256) ? scan[tid + off] : 0u;
    __syncthreads();
    scan[tid] += add;
    __syncthreads();
  }
  unsigned inclusive = scan[tid];
  unsigned after = inclusive - local;
  if (after < kth && inclusive >= kth) {
    unsigned g = after;
    for (int b = 15; b >= 0; --b) {
      unsigned c = hist[base + b];
      if (g + c >= kth) { *out_b = (unsigned)(base + b); *out_g = g; break; }
      g += c;
    }
  }
  __syncthreads();
}

// ---- kFused: one coalesced pass over probs -> bg bits + per-(b,c,chunk) candidates
// 256 threads per 128-row tile; 2 threads per row (halves join via shfl_xor).
__global__ __launch_bounds__(256) void kFused(const float* __restrict__ probs,
                                              unsigned long long* __restrict__ bgm,
                                              unsigned* __restrict__ pcnt,
                                              float* __restrict__ cand_val,
                                              int* __restrict__ cand_idx) {
  int gid = blockIdx.x;            // 0..1023
  int b = gid >> 7;                // / NCHUNK_
  int q = gid & (NCHUNK_ - 1);
  int tid = threadIdx.x;           // 0..255

  __shared__ float tile[CHUNK_ * C_];       // 41.5 KB
  __shared__ float lval[C_][CAPC_];         // 5.2 KB
  __shared__ int   lidx[C_][CAPC_];         // 5.2 KB
  __shared__ unsigned lcnt[C_];
  __shared__ unsigned char bgb[CHUNK_];

  // stage 128 rows, coalesced float4 (base 16B-aligned: 128*324B = 2592*16B)
  const float4* src4 = (const float4*)(probs + ((size_t)b * N_ + (size_t)q * CHUNK_) * C_);
  float4* tile4 = (float4*)tile;
  for (int i = tid; i < (CHUNK_ * C_) / 4; i += 256) tile4[i] = src4[i];
  if (tid < C_) lcnt[tid] = 0;
  __syncthreads();

  // 2 threads per row: half 0 -> cols 1..40, half 1 -> cols 41..80
  int r = tid >> 1;                // row 0..127
  int half = tid & 1;
  const float* row = &tile[r * C_];
  float p0 = row[0];
  int j0 = 1 + half * 40;
  float hm = -1.0f;
  for (int j = j0; j < j0 + 40; ++j) hm = fmaxf(hm, row[j]);
  float mx = fmaxf(hm, __shfl_xor(hm, 1));
  bool bg = (p0 >= mx);
  if (half == 0) bgb[r] = bg ? 1 : 0;
  if (!bg) {
    int n = q * CHUNK_ + r;        // row index within batch b
    if (half == 0 && p0 > TAU0_) {
      unsigned s = atomicAdd(&lcnt[0], 1u);
      if (s < CAPC_) { lval[0][s] = p0; lidx[0][s] = n; }
    }
    for (int j = j0; j < j0 + 40; ++j) {
      float v = row[j];
      if (v > TAU_) {
        unsigned s = atomicAdd(&lcnt[j], 1u);
        if (s < CAPC_) { lval[j][s] = v; lidx[j][s] = n; }
      }
    }
  }
  __syncthreads();

  // bg bitmask: waves 0/1 ballot rows 0..63 / 64..127
  if (tid < CHUNK_) {
    unsigned long long bal = __ballot(bgb[tid] != 0);
    if ((tid & 63) == 0)
      bgm[(((size_t)b * N_ + (size_t)q * CHUNK_) >> 6) + (tid >> 6)] = bal;
  }
  // flush lists: deterministic segment per (b,c,chunk); raw count (overflow detectable)
  if (tid < C_) {
    unsigned lc = lcnt[tid];
    unsigned wr = lc < CAPC_ ? lc : CAPC_;
    size_t seg = ((size_t)(b * C_ + tid) * NCHUNK_ + q);
    pcnt[seg] = lc;
    float* dv = cand_val + seg * CAPC_;
    int*   di = cand_idx + seg * CAPC_;
    for (unsigned s = 0; s < wr; ++s) { dv[s] = lval[tid][s]; di[s] = lidx[tid][s]; }
  }
}

// ---- k_sel: per-(b,c) exact top-100 + decode + single-wave NMS --------------------
__global__ __launch_bounds__(256) void k_sel(const float* __restrict__ probs,
                                             const unsigned long long* __restrict__ bgm,
                                             const unsigned* __restrict__ pcnt,
                                             const float* __restrict__ cand_val,
                                             const int* __restrict__ cand_idx,
                                             const float* __restrict__ roi,
                                             const float* __restrict__ deltas,
                                             float* __restrict__ top_sc,
                                             float* __restrict__ top_box,
                                             int* __restrict__ keep_out) {
  int bc = blockIdx.x;
  int b = bc / C_, c = bc % C_;
  int tid = threadIdx.x;
  __shared__ float cv[CAP_];
  __shared__ int   ci[CAP_];
  __shared__ unsigned spc[NCHUNK_];
  __shared__ int     spre[NCHUNK_ + 1];
  __shared__ int     s_total;
  __shared__ int     s_ovf;
  __shared__ float selv[K_];
  __shared__ int   seli[K_];
  __shared__ float bx0[K_], bx1[K_], bx2[K_], bx3[K_], bar[K_];
  __shared__ unsigned chosen[N_ / 32];   // fallback only (2 KB)
  __shared__ float rv[4];
  __shared__ int   ri[4];

  if (tid == 0) s_ovf = 0;
  for (int t = tid; t < NCHUNK_; t += 256) {
    unsigned lc = pcnt[(size_t)bc * NCHUNK_ + t];
    spc[t] = lc;
    if (lc > CAPC_) atomicOr(&s_ovf, 1);
  }
  __syncthreads();
  if (tid == 0) {
    int acc = 0;
    for (int qq = 0; qq < NCHUNK_; ++qq) {
      spre[qq] = acc;
      unsigned lc = spc[qq];
      acc += (int)(lc < CAPC_ ? lc : CAPC_);
    }
    spre[NCHUNK_] = acc;
    s_total = acc;
  }
  __syncthreads();
  int total = s_total;
  bool fast = (!s_ovf && total >= K_ && total <= CAP_);

  if (fast) {
    for (int t = tid; t < NCHUNK_ * CAPC_; t += 256) {
      int qq = t >> 4, s = t & (CAPC_ - 1);
      if ((unsigned)s < spc[qq]) {
        size_t seg = (size_t)bc * NCHUNK_ + qq;
        int pos = spre[qq] + s;
        cv[pos] = cand_val[seg * CAPC_ + s];
        ci[pos] = cand_idx[seg * CAPC_ + s];
      }
    }
    __syncthreads();
    for (int t = tid; t < total; t += 256) {
      float mv = cv[t];
      int   mi = ci[t];
      int rank = 0;
      for (int j = 0; j < total; ++j) {
        float v = cv[j]; int ji = ci[j];
        rank += (v > mv || (v == mv && ji < mi)) ? 1 : 0;
      }
      if (rank < K_) { selv[rank] = mv; seli[rank] = mi; }
    }
    __syncthreads();
  } else {
    // exact fallback: iterative top-100 over the full score column (stat. never taken)
    for (int i = tid; i < N_ / 32; i += 256) chosen[i] = 0u;
    __syncthreads();
    for (int k = 0; k < K_; ++k) {
      float bv = -1.0f;
      int   bi = 0;
      for (int n = tid; n < N_; n += 256) {
        if ((chosen[n >> 5] >> (n & 31)) & 1u) continue;
        unsigned long long w = bgm[((size_t)b * N_ + n) >> 6];
        float v = ((w >> (n & 63)) & 1ull) ? 0.0f
                 : probs[((size_t)b * N_ + n) * C_ + c];
        if (v > bv || (v == bv && n < bi)) { bv = v; bi = n; }
      }
      int lane = tid & 63, wave = tid >> 6;
      for (int off = 32; off > 0; off >>= 1) {
        float ov = __shfl_down(bv, off);
        int   oi = __shfl_down(bi, off);
        if (ov > bv || (ov == bv && oi < bi)) { bv = ov; bi = oi; }
      }
      if (lane == 0) { rv[wave] = bv; ri[wave] = bi; }
      __syncthreads();
      if (tid == 0) {
        float fv = rv[0]; int fi = ri[0];
        for (int w2 = 1; w2 < 4; ++w2)
          if (rv[w2] > fv || (rv[w2] == fv && ri[w2] < fi)) { fv = rv[w2]; fi = ri[w2]; }
        selv[k] = fv; seli[k] = fi;
        chosen[fi >> 5] |= (1u << (fi & 31));
      }
      __syncthreads();
    }
  }

  // decode + clip; write top_sc/top_box
  if (tid < K_) {
    int n = seli[tid];
    float4 a = *(const float4*)(roi + ((size_t)b * N_ + n) * 4);
    float4 d = *(const float4*)(deltas + ((size_t)b * N_ + n) * (C_ * 4) + (c << 2));
    float aw = a.w - a.y, ah = a.z - a.x;
    float acx = a.y + 0.5f * aw, acy = a.x + 0.5f * ah;
    float d0 = d.x * 0.1f, d1 = d.y * 0.1f, d2 = d.z * 0.2f, d3 = d.w * 0.2f;
    float bw = expf(d3) * aw, bh = expf(d2) * ah;
    float bcx = d1 * aw + acx, bcy = d0 * ah + acy;
    float y1 = bcy - 0.5f * bh, x1 = bcx - 0.5f * bw;
    float y2 = bh + y1, x2 = bw + x1;
    y1 = fminf(fmaxf(y1, 0.0f), 1.0f);
    x1 = fminf(fmaxf(x1, 0.0f), 1.0f);
    y2 = fminf(fmaxf(y2, 0.0f), 1.0f);
    x2 = fminf(fmaxf(x2, 0.0f), 1.0f);
    bx0[tid] = y1; bx1[tid] = x1; bx2[tid] = y2; bx3[tid] = x2;
    bar[tid] = (y2 - y1) * (x2 - x1);
    top_sc[bc * K_ + tid] = selv[tid];
    *(float4*)(top_box + ((size_t)bc * K_ + tid) * 4) = make_float4(y1, x1, y2, x2);
  }
  __syncthreads();

  // single-wave barrier-free NMS (wave 0; 2 boxes per lane)
  if (tid < 64) {
    float Ay1 = bx0[tid], Ax1 = bx1[tid], Ay2 = bx2[tid], Ax2 = bx3[tid], Aar = bar[tid];
    int hasB = (tid + 64 < K_);
    float By1 = 0, Bxx1 = 0, By2 = 0, Bxx2 = 0, Bar2 = 0;
    if (hasB) { By1 = bx0[tid+64]; Bxx1 = bx1[tid+64]; By2 = bx2[tid+64]; Bxx2 = bx3[tid+64]; Bar2 = bar[tid+64]; }
    int ka = 1, kb = hasB;
    for (int i = 0; i < K_; ++i) {
      int src = i & 63;
      bool hi = (i >= 64);
      float iy1 = __shfl(hi ? By1 : Ay1, src);
      float ix1 = __shfl(hi ? Bxx1 : Ax1, src);
      float iy2 = __shfl(hi ? By2 : Ay2, src);
      float ix2 = __shfl(hi ? Bxx2 : Ax2, src);
      float iar = __shfl(hi ? Bar2 : Aar, src);
      int   ki  = __shfl(hi ? kb : ka, src);
      if (ki) {
        if (ka && tid > i) {
          float yy1 = fmaxf(iy1, Ay1), xx1 = fmaxf(ix1, Ax1);
          float yy2 = fminf(iy2, Ay2), xx2 = fminf(ix2, Ax2);
          float inter = fmaxf(yy2 - yy1, 0.0f) * fmaxf(xx2 - xx1, 0.0f);
          float uni = iar + Aar - inter;
          if (inter / fmaxf(uni, 1e-12f) > IOU_THR_) ka = 0;
        }
        if (kb && (tid + 64) > i) {
          float yy1 = fmaxf(iy1, By1), xx1 = fmaxf(ix1, Bxx1);
          float yy2 = fminf(iy2, By2), xx2 = fminf(ix2, Bxx2);
          float inter = fmaxf(yy2 - yy1, 0.0f) * fmaxf(xx2 - xx1, 0.0f);
          float uni = iar + Bar2 - inter;
          if (inter / fmaxf(uni, 1e-12f) > IOU_THR_) kb = 0;
        }
      }
    }
    keep_out[bc * K_ + tid] = ka;
    if (hasB) keep_out[bc * K_ + tid + 64] = kb;
  }
}

// ---- k4: per-batch exact top-100 over 8100 keyed values ---------------------------
__global__ __launch_bounds__(256) void k4_final(const float* __restrict__ top_sc,
                                                const float* __restrict__ top_box,
                                                const int* __restrict__ keep_in,
                                                float* __restrict__ out) {
  int b = blockIdx.x;
  int tid = threadIdx.x;
  __shared__ float keyed[M_];
  __shared__ unsigned hist[4096];
  __shared__ unsigned scan[256];
  __shared__ unsigned s_b1, s_g1, s_b2, s_g2, s_cnt;
  __shared__ float cv[KCAP_];
  __shared__ int   ci[KCAP_];
  __shared__ int   sel_m[K_];
  __shared__ float sel_v[K_];

  for (int m = tid; m < M_; m += 256)
    keyed[m] = keep_in[b * M_ + m] ? top_sc[b * M_ + m] : NEG_;
  for (int i = tid; i < 4096; i += 256) hist[i] = 0;
  if (tid == 0) s_cnt = 0;
  __syncthreads();
  for (int m = tid; m < M_; m += 256) atomicAdd(&hist[key_of(keyed[m]) >> 20], 1u);
  __syncthreads();
  find_kth_bin(hist, scan, K_, &s_b1, &s_g1);
  unsigned b1 = s_b1;
  unsigned need1 = K_ - s_g1;
  __syncthreads();
  for (int i = tid; i < 4096; i += 256) hist[i] = 0;
  __syncthreads();
  for (int m = tid; m < M_; m += 256) {
    unsigned k = key_of(keyed[m]);
    if ((k >> 20) == b1) atomicAdd(&hist[(k >> 8) & 0xFFFu], 1u);
  }
  __syncthreads();
  find_kth_bin(hist, scan, need1, &s_b2, &s_g2);
  unsigned t24 = (b1 << 12) | s_b2;
  __syncthreads();
  for (int m = tid; m < M_; m += 256) {
    float v = keyed[m];
    unsigned k = key_of(v);
    if ((k >> 8) >= t24) {
      unsigned p = atomicAdd(&s_cnt, 1u);
      if (p < KCAP_) { cv[p] = v; ci[p] = m; }
    }
  }
  __syncthreads();
  int cnt = (int)min(s_cnt, (unsigned)KCAP_);
  if (tid < cnt) {
    float mv = cv[tid];
    int   mi = ci[tid];
    int rank = 0;
    for (int j = 0; j < cnt; ++j) {
      float v = cv[j]; int ji = ci[j];
      rank += (v > mv || (v == mv && ji < mi)) ? 1 : 0;
    }
    if (rank < K_) { sel_m[rank] = mi; sel_v[rank] = mv; }
  }
  __syncthreads();

  float* ob = out;                 // (B,K,4)
  float* oc = out + B_ * K_ * 4;   // (B,K)
  float* os = oc + B_ * K_;        // (B,K)
  if (tid < K_) {
    int m = sel_m[tid];
    float kv = sel_v[tid];
    bool valid = kv > (NEG_ * 0.5f);
    float4 bb = *(const float4*)(top_box + ((size_t)b * M_ + m) * 4);
    float sv = top_sc[b * M_ + m];
    float cls = (float)(m / K_);
    float4 o = valid ? bb : make_float4(0.f, 0.f, 0.f, 0.f);
    *(float4*)(ob + ((size_t)b * K_ + tid) * 4) = o;
    oc[b * K_ + tid] = valid ? cls : 0.0f;
    os[b * K_ + tid] = valid ? sv : 0.0f;
  }
}

extern "C" void kernel_launch(void* const* d_in, const int* in_sizes, int n_in,
                              void* d_out, int out_size, void* d_ws, size_t ws_size,
                              hipStream_t stream) {
  const float* roi    = (const float*)d_in[0];   // (B,N,4)
  const float* deltas = (const float*)d_in[1];   // (B,N,C*4)
  const float* probs  = (const float*)d_in[2];   // (B,N,C)
  float* out = (float*)d_out;

  char* ws = (char*)d_ws;
  size_t off = 0;
  unsigned long long* bgm = (unsigned long long*)(ws + off);
  off += (size_t)B_ * N_ / 64 * sizeof(unsigned long long);         // 16 KB
  unsigned* pcnt = (unsigned*)(ws + off);
  off += (size_t)B_ * C_ * NCHUNK_ * sizeof(unsigned);              // 324 KB
  float* cand_val = (float*)(ws + off);
  off += (size_t)B_ * C_ * NCHUNK_ * CAPC_ * sizeof(float);         // 5.3 MB
  int* cand_idx = (int*)(ws + off);
  off += (size_t)B_ * C_ * NCHUNK_ * CAPC_ * sizeof(int);           // 5.3 MB
  float* top_sc = (float*)(ws + off);  off += (size_t)B_ * M_ * sizeof(float);
  float* top_box = (float*)(ws + off); off += (size_t)B_ * M_ * 4 * sizeof(float);
  int* keepA = (int*)(ws + off);       off += (size_t)B_ * M_ * sizeof(int);
  (void)ws_size; (void)in_sizes; (void)n_in; (void)out_size;

  kFused<<<B_ * NCHUNK_, 256, 0, stream>>>(probs, bgm, pcnt, cand_val, cand_idx);
  k_sel<<<B_ * C_, 256, 0, stream>>>(probs, bgm, pcnt, cand_val, cand_idx,
                                     roi, deltas, top_sc, top_box, keepA);
  k4_final<<<B_, 256, 0, stream>>>(top_sc, top_box, keepA, out);
}

// Round 6
// 117.275 us; speedup vs baseline: 2.9666x; 1.0112x over previous
//
#include <hip/hip_runtime.h>

#define B_ 8
#define N_ 16384
#define C_ 81
#define K_ 100
#define M_ (C_ * K_)          // 8100
#define NEG_ (-1e30f)
#define IOU_THR_ 0.5f
#define TAU0_ 0.96f           // class-0 threshold (bg rule depletes its tail)
#define TAU_ 0.985f           // classes >= 1
#define CHUNK_ 64             // rows per kFused block
#define NCHUNK_ (N_ / CHUNK_) // 256
#define CAPC_ 16              // per-class per-chunk candidate cap
#define CAP_ 768              // k_sel gather capacity
#define KCAP_ 256             // k4 compaction capacity

// monotone key: order of key_of(v) == order of v (all floats)
__device__ inline unsigned key_of(float v) {
  unsigned u = __float_as_uint(v);
  return u ^ ((unsigned)((int)u >> 31) | 0x80000000u);
}

__device__ inline void find_kth_bin(unsigned* hist, unsigned* scan, unsigned kth,
                                    unsigned* out_b, unsigned* out_g) {
  int tid = threadIdx.x;
  int base = tid << 4;
  unsigned local = 0;
#pragma unroll
  for (int i = 0; i < 16; ++i) local += hist[base + ((tid + i) & 15)];
  scan[tid] = local;
  __syncthreads();
  for (int off = 1; off < 256; off <<= 1) {
    unsigned add = (tid + off < 256) ? scan[tid + off] : 0u;
    __syncthreads();
    scan[tid] += add;
    __syncthreads();
  }
  unsigned inclusive = scan[tid];
  unsigned after = inclusive - local;
  if (after < kth && inclusive >= kth) {
    unsigned g = after;
    for (int b = 15; b >= 0; --b) {
      unsigned c = hist[base + b];
      if (g + c >= kth) { *out_b = (unsigned)(base + b); *out_g = g; break; }
      g += c;
    }
  }
  __syncthreads();
}

// ---- kFused: one coalesced pass over probs -> bg bits + per-(b,c,chunk) candidates
// 256 threads per 64-row tile; 4 threads per row (cols split 20/20/20/20).
__global__ __launch_bounds__(256) void kFused(const float* __restrict__ probs,
                                              unsigned long long* __restrict__ bgm,
                                              unsigned* __restrict__ pcnt,
                                              float* __restrict__ cand_val,
                                              int* __restrict__ cand_idx) {
  int gid = blockIdx.x;            // 0..2047
  int b = gid >> 8;                // / NCHUNK_
  int q = gid & (NCHUNK_ - 1);
  int tid = threadIdx.x;           // 0..255

  __shared__ float tile[CHUNK_ * C_];       // 64*81*4 = 20.7 KB
  __shared__ float lval[C_][CAPC_];         // 5.2 KB
  __shared__ int   lidx[C_][CAPC_];         // 5.2 KB
  __shared__ unsigned lcnt[C_];
  __shared__ unsigned char bgb[CHUNK_];

  // stage 64 rows, coalesced float4 (base 16B-aligned: 64*324B = 1296*16B)
  const float4* src4 = (const float4*)(probs + ((size_t)b * N_ + (size_t)q * CHUNK_) * C_);
  float4* tile4 = (float4*)tile;
  for (int i = tid; i < (CHUNK_ * C_) / 4; i += 256) tile4[i] = src4[i];
  if (tid < C_) lcnt[tid] = 0;
  __syncthreads();

  // 4 threads per row: sub t covers cols [1+20t, 20+20t]; t0 also handles col 0
  int r = tid >> 2;                // row 0..63
  int t = tid & 3;
  int lane = tid & 63;
  const float* row = &tile[r * C_];
  int j0 = 1 + t * 20;
  float hm = -1.0f;
  for (int j = j0; j < j0 + 20; ++j) hm = fmaxf(hm, row[j]);
  hm = fmaxf(hm, __shfl_xor(hm, 1));
  hm = fmaxf(hm, __shfl_xor(hm, 2));           // max over cols 1..80, all 4 threads
  float p0 = row[0];                           // same LDS word for the 4-group (broadcast)
  bool bg = (p0 >= hm);
  if (t == 0) bgb[r] = bg ? 1 : 0;
  if (!bg) {
    int n = q * CHUNK_ + r;        // row index within batch b
    if (t == 0 && p0 > TAU0_) {
      unsigned s = atomicAdd(&lcnt[0], 1u);
      if (s < CAPC_) { lval[0][s] = p0; lidx[0][s] = n; }
    }
    for (int j = j0; j < j0 + 20; ++j) {
      float v = row[j];
      if (v > TAU_) {
        unsigned s = atomicAdd(&lcnt[j], 1u);
        if (s < CAPC_) { lval[j][s] = v; lidx[j][s] = n; }
      }
    }
  }
  __syncthreads();

  // bg bitmask: wave 0 ballots the 64 rows -> one 64-bit word
  if (tid < CHUNK_) {
    unsigned long long bal = __ballot(bgb[tid] != 0);
    if (lane == 0) bgm[(size_t)b * NCHUNK_ + q] = bal;
  }
  // flush lists: deterministic segment per (b,c,chunk); raw count (overflow detectable)
  if (tid < C_) {
    unsigned lc = lcnt[tid];
    unsigned wr = lc < CAPC_ ? lc : CAPC_;
    size_t seg = ((size_t)(b * C_ + tid) * NCHUNK_ + q);
    pcnt[seg] = lc;
    float* dv = cand_val + seg * CAPC_;
    int*   di = cand_idx + seg * CAPC_;
    for (unsigned s = 0; s < wr; ++s) { dv[s] = lval[tid][s]; di[s] = lidx[tid][s]; }
  }
}

// ---- k_sel: per-(b,c) exact top-100 + decode + single-wave NMS --------------------
__global__ __launch_bounds__(256) void k_sel(const float* __restrict__ probs,
                                             const unsigned long long* __restrict__ bgm,
                                             const unsigned* __restrict__ pcnt,
                                             const float* __restrict__ cand_val,
                                             const int* __restrict__ cand_idx,
                                             const float* __restrict__ roi,
                                             const float* __restrict__ deltas,
                                             float* __restrict__ top_sc,
                                             float* __restrict__ top_box,
                                             int* __restrict__ keep_out) {
  int bc = blockIdx.x;
  int b = bc / C_, c = bc % C_;
  int tid = threadIdx.x;
  __shared__ float cv[CAP_];
  __shared__ int   ci[CAP_];
  __shared__ unsigned spc[NCHUNK_];          // raw counts (one per chunk; 256 == blockDim)
  __shared__ int     sscan[NCHUNK_];
  __shared__ int     spre[NCHUNK_];
  __shared__ int     s_total;
  __shared__ int     s_ovf;
  __shared__ float selv[K_];
  __shared__ int   seli[K_];
  __shared__ float bx0[K_], bx1[K_], bx2[K_], bx3[K_], bar[K_];
  __shared__ unsigned chosen[N_ / 32];   // fallback only (2 KB)
  __shared__ float rv[4];
  __shared__ int   ri[4];

  if (tid == 0) s_ovf = 0;
  {
    unsigned lc = pcnt[(size_t)bc * NCHUNK_ + tid];
    spc[tid] = lc;
    if (lc > CAPC_) atomicOr(&s_ovf, 1);
    int own = (int)(lc < CAPC_ ? lc : CAPC_);
    sscan[tid] = own;
    __syncthreads();
    // Hillis-Steele inclusive scan over 256 entries
    for (int off = 1; off < 256; off <<= 1) {
      int add = (tid >= off) ? sscan[tid - off] : 0;
      __syncthreads();
      sscan[tid] += add;
      __syncthreads();
    }
    spre[tid] = sscan[tid] - own;
    if (tid == 255) s_total = sscan[255];
  }
  __syncthreads();
  int total = s_total;
  bool fast = (!s_ovf && total >= K_ && total <= CAP_);

  if (fast) {
    for (int t = tid; t < NCHUNK_ * CAPC_; t += 256) {
      int qq = t >> 4, s = t & (CAPC_ - 1);
      if ((unsigned)s < spc[qq]) {
        size_t seg = (size_t)bc * NCHUNK_ + qq;
        int pos = spre[qq] + s;
        cv[pos] = cand_val[seg * CAPC_ + s];
        ci[pos] = cand_idx[seg * CAPC_ + s];
      }
    }
    __syncthreads();
    for (int t = tid; t < total; t += 256) {
      float mv = cv[t];
      int   mi = ci[t];
      int rank = 0;
      for (int j = 0; j < total; ++j) {
        float v = cv[j]; int ji = ci[j];
        rank += (v > mv || (v == mv && ji < mi)) ? 1 : 0;
      }
      if (rank < K_) { selv[rank] = mv; seli[rank] = mi; }
    }
    __syncthreads();
  } else {
    // exact fallback: iterative top-100 over the full score column (stat. never taken)
    for (int i = tid; i < N_ / 32; i += 256) chosen[i] = 0u;
    __syncthreads();
    for (int k = 0; k < K_; ++k) {
      float bv = -1.0f;
      int   bi = 0;
      for (int n = tid; n < N_; n += 256) {
        if ((chosen[n >> 5] >> (n & 31)) & 1u) continue;
        unsigned long long w = bgm[((size_t)b * N_ + n) >> 6];
        float v = ((w >> (n & 63)) & 1ull) ? 0.0f
                 : probs[((size_t)b * N_ + n) * C_ + c];
        if (v > bv || (v == bv && n < bi)) { bv = v; bi = n; }
      }
      int lane = tid & 63, wave = tid >> 6;
      for (int off = 32; off > 0; off >>= 1) {
        float ov = __shfl_down(bv, off);
        int   oi = __shfl_down(bi, off);
        if (ov > bv || (ov == bv && oi < bi)) { bv = ov; bi = oi; }
      }
      if (lane == 0) { rv[wave] = bv; ri[wave] = bi; }
      __syncthreads();
      if (tid == 0) {
        float fv = rv[0]; int fi = ri[0];
        for (int w2 = 1; w2 < 4; ++w2)
          if (rv[w2] > fv || (rv[w2] == fv && ri[w2] < fi)) { fv = rv[w2]; fi = ri[w2]; }
        selv[k] = fv; seli[k] = fi;
        chosen[fi >> 5] |= (1u << (fi & 31));
      }
      __syncthreads();
    }
  }

  // decode + clip; write top_sc/top_box
  if (tid < K_) {
    int n = seli[tid];
    float4 a = *(const float4*)(roi + ((size_t)b * N_ + n) * 4);
    float4 d = *(const float4*)(deltas + ((size_t)b * N_ + n) * (C_ * 4) + (c << 2));
    float aw = a.w - a.y, ah = a.z - a.x;
    float acx = a.y + 0.5f * aw, acy = a.x + 0.5f * ah;
    float d0 = d.x * 0.1f, d1 = d.y * 0.1f, d2 = d.z * 0.2f, d3 = d.w * 0.2f;
    float bw = expf(d3) * aw, bh = expf(d2) * ah;
    float bcx = d1 * aw + acx, bcy = d0 * ah + acy;
    float y1 = bcy - 0.5f * bh, x1 = bcx - 0.5f * bw;
    float y2 = bh + y1, x2 = bw + x1;
    y1 = fminf(fmaxf(y1, 0.0f), 1.0f);
    x1 = fminf(fmaxf(x1, 0.0f), 1.0f);
    y2 = fminf(fmaxf(y2, 0.0f), 1.0f);
    x2 = fminf(fmaxf(x2, 0.0f), 1.0f);
    bx0[tid] = y1; bx1[tid] = x1; bx2[tid] = y2; bx3[tid] = x2;
    bar[tid] = (y2 - y1) * (x2 - x1);
    top_sc[bc * K_ + tid] = selv[tid];
    *(float4*)(top_box + ((size_t)bc * K_ + tid) * 4) = make_float4(y1, x1, y2, x2);
  }
  __syncthreads();

  // single-wave barrier-free NMS (wave 0; 2 boxes per lane)
  if (tid < 64) {
    float Ay1 = bx0[tid], Ax1 = bx1[tid], Ay2 = bx2[tid], Ax2 = bx3[tid], Aar = bar[tid];
    int hasB = (tid + 64 < K_);
    float By1 = 0, Bxx1 = 0, By2 = 0, Bxx2 = 0, Bar2 = 0;
    if (hasB) { By1 = bx0[tid+64]; Bxx1 = bx1[tid+64]; By2 = bx2[tid+64]; Bxx2 = bx3[tid+64]; Bar2 = bar[tid+64]; }
    int ka = 1, kb = hasB;
    for (int i = 0; i < K_; ++i) {
      int src = i & 63;
      bool hi = (i >= 64);
      float iy1 = __shfl(hi ? By1 : Ay1, src);
      float ix1 = __shfl(hi ? Bxx1 : Ax1, src);
      float iy2 = __shfl(hi ? By2 : Ay2, src);
      float ix2 = __shfl(hi ? Bxx2 : Ax2, src);
      float iar = __shfl(hi ? Bar2 : Aar, src);
      int   ki  = __shfl(hi ? kb : ka, src);
      if (ki) {
        if (ka && tid > i) {
          float yy1 = fmaxf(iy1, Ay1), xx1 = fmaxf(ix1, Ax1);
          float yy2 = fminf(iy2, Ay2), xx2 = fminf(ix2, Ax2);
          float inter = fmaxf(yy2 - yy1, 0.0f) * fmaxf(xx2 - xx1, 0.0f);
          float uni = iar + Aar - inter;
          if (inter / fmaxf(uni, 1e-12f) > IOU_THR_) ka = 0;
        }
        if (kb && (tid + 64) > i) {
          float yy1 = fmaxf(iy1, By1), xx1 = fmaxf(ix1, Bxx1);
          float yy2 = fminf(iy2, By2), xx2 = fminf(ix2, Bxx2);
          float inter = fmaxf(yy2 - yy1, 0.0f) * fmaxf(xx2 - xx1, 0.0f);
          float uni = iar + Bar2 - inter;
          if (inter / fmaxf(uni, 1e-12f) > IOU_THR_) kb = 0;
        }
      }
    }
    keep_out[bc * K_ + tid] = ka;
    if (hasB) keep_out[bc * K_ + tid + 64] = kb;
  }
}

// ---- k4: per-batch exact top-100 over 8100 keyed values ---------------------------
__global__ __launch_bounds__(256) void k4_final(const float* __restrict__ top_sc,
                                                const float* __restrict__ top_box,
                                                const int* __restrict__ keep_in,
                                                float* __restrict__ out) {
  int b = blockIdx.x;
  int tid = threadIdx.x;
  __shared__ float keyed[M_];
  __shared__ unsigned hist[4096];
  __shared__ unsigned scan[256];
  __shared__ unsigned s_b1, s_g1, s_b2, s_g2, s_cnt;
  __shared__ float cv[KCAP_];
  __shared__ int   ci[KCAP_];
  __shared__ int   sel_m[K_];
  __shared__ float sel_v[K_];

  for (int m = tid; m < M_; m += 256)
    keyed[m] = keep_in[b * M_ + m] ? top_sc[b * M_ + m] : NEG_;
  for (int i = tid; i < 4096; i += 256) hist[i] = 0;
  if (tid == 0) s_cnt = 0;
  __syncthreads();
  for (int m = tid; m < M_; m += 256) atomicAdd(&hist[key_of(keyed[m]) >> 20], 1u);
  __syncthreads();
  find_kth_bin(hist, scan, K_, &s_b1, &s_g1);
  unsigned b1 = s_b1;
  unsigned need1 = K_ - s_g1;
  __syncthreads();
  for (int i = tid; i < 4096; i += 256) hist[i] = 0;
  __syncthreads();
  for (int m = tid; m < M_; m += 256) {
    unsigned k = key_of(keyed[m]);
    if ((k >> 20) == b1) atomicAdd(&hist[(k >> 8) & 0xFFFu], 1u);
  }
  __syncthreads();
  find_kth_bin(hist, scan, need1, &s_b2, &s_g2);
  unsigned t24 = (b1 << 12) | s_b2;
  __syncthreads();
  for (int m = tid; m < M_; m += 256) {
    float v = keyed[m];
    unsigned k = key_of(v);
    if ((k >> 8) >= t24) {
      unsigned p = atomicAdd(&s_cnt, 1u);
      if (p < KCAP_) { cv[p] = v; ci[p] = m; }
    }
  }
  __syncthreads();
  int cnt = (int)min(s_cnt, (unsigned)KCAP_);
  if (tid < cnt) {
    float mv = cv[tid];
    int   mi = ci[tid];
    int rank = 0;
    for (int j = 0; j < cnt; ++j) {
      float v = cv[j]; int ji = ci[j];
      rank += (v > mv || (v == mv && ji < mi)) ? 1 : 0;
    }
    if (rank < K_) { sel_m[rank] = mi; sel_v[rank] = mv; }
  }
  __syncthreads();

  float* ob = out;                 // (B,K,4)
  float* oc = out + B_ * K_ * 4;   // (B,K)
  float* os = oc + B_ * K_;        // (B,K)
  if (tid < K_) {
    int m = sel_m[tid];
    float kv = sel_v[tid];
    bool valid = kv > (NEG_ * 0.5f);
    float4 bb = *(const float4*)(top_box + ((size_t)b * M_ + m) * 4);
    float sv = top_sc[b * M_ + m];
    float cls = (float)(m / K_);
    float4 o = valid ? bb : make_float4(0.f, 0.f, 0.f, 0.f);
    *(float4*)(ob + ((size_t)b * K_ + tid) * 4) = o;
    oc[b * K_ + tid] = valid ? cls : 0.0f;
    os[b * K_ + tid] = valid ? sv : 0.0f;
  }
}

extern "C" void kernel_launch(void* const* d_in, const int* in_sizes, int n_in,
                              void* d_out, int out_size, void* d_ws, size_t ws_size,
                              hipStream_t stream) {
  const float* roi    = (const float*)d_in[0];   // (B,N,4)
  const float* deltas = (const float*)d_in[1];   // (B,N,C*4)
  const float* probs  = (const float*)d_in[2];   // (B,N,C)
  float* out = (float*)d_out;

  char* ws = (char*)d_ws;
  size_t off = 0;
  unsigned long long* bgm = (unsigned long long*)(ws + off);
  off += (size_t)B_ * NCHUNK_ * sizeof(unsigned long long);         // 16 KB
  unsigned* pcnt = (unsigned*)(ws + off);
  off += (size_t)B_ * C_ * NCHUNK_ * sizeof(unsigned);              // 663 KB
  float* cand_val = (float*)(ws + off);
  off += (size_t)B_ * C_ * NCHUNK_ * CAPC_ * sizeof(float);         // 10.6 MB
  int* cand_idx = (int*)(ws + off);
  off += (size_t)B_ * C_ * NCHUNK_ * CAPC_ * sizeof(int);           // 10.6 MB
  float* top_sc = (float*)(ws + off);  off += (size_t)B_ * M_ * sizeof(float);
  float* top_box = (float*)(ws + off); off += (size_t)B_ * M_ * 4 * sizeof(float);
  int* keepA = (int*)(ws + off);       off += (size_t)B_ * M_ * sizeof(int);
  (void)ws_size; (void)in_sizes; (void)n_in; (void)out_size;

  kFused<<<B_ * NCHUNK_, 256, 0, stream>>>(probs, bgm, pcnt, cand_val, cand_idx);
  k_sel<<<B_ * C_, 256, 0, stream>>>(probs, bgm, pcnt, cand_val, cand_idx,
                                     roi, deltas, top_sc, top_box, keepA);
  k4_final<<<B_, 256, 0, stream>>>(top_sc, top_box, keepA, out);
}